// Round 15
// baseline (60.888 us; speedup 1.0000x reference)
//
#include <hip/hip_runtime.h>
#include <hip/hip_bf16.h>
#include <hip/hip_fp16.h>

#define D 8192
#define NPAIR 523776.0

typedef short short8 __attribute__((ext_vector_type(8)));
typedef float f32x4 __attribute__((ext_vector_type(4)));
typedef _Float16 f16x8 __attribute__((ext_vector_type(8)));
typedef int int32x4 __attribute__((ext_vector_type(4)));

#define GLOAD_LDS(G, L) __builtin_amdgcn_global_load_lds( \
    (const __attribute__((address_space(1))) void*)(G),   \
    (__attribute__((address_space(3))) void*)(L), 16, 0, 0)

__device__ __forceinline__ short8 cvt8(const float4 a, const float4 b) {
    union { short8 s; __hip_bfloat162 h[4]; } u;
    u.h[0] = __float22bfloat162_rn(make_float2(a.x, a.y));
    u.h[1] = __float22bfloat162_rn(make_float2(a.z, a.w));
    u.h[2] = __float22bfloat162_rn(make_float2(b.x, b.y));
    u.h[3] = __float22bfloat162_rn(make_float2(b.z, b.w));
    return u.s;
}

__device__ __forceinline__ int q8(float x) {
    return __float2int_rn(fminf(fmaxf(x * 32.f, -127.f), 127.f));
}
__device__ __forceinline__ int pack4(float a, float b, float c, float d) {
    return (q8(a) & 255) | ((q8(b) & 255) << 8) | ((q8(c) & 255) << 16) | ((q8(d) & 255) << 24);
}

// ---- 2048 blocks, bid = x(0..7, XCD) + 8*s, s in 0..255.  m = x>>2, xr = x&3.
// DIAG FIRST: s < 32: diag tile dt = s&7, chunk c16 = (s>>3)*4 + xr (16 chunks of K=512, 8 slabs)
//             s >= 32: off-diag sp = s-32: c32 = (sp/28)*4 + xr (32 chunks of K=256, 4 slabs),
//                      tt = sp%28 -> triangular (ti,tj)
__device__ __forceinline__ void decode_bid(int bid, int& m, int& ti, int& tj, int& ks0, bool& diag) {
    int x = bid & 7, s = bid >> 3;
    m = x >> 2;
    int xr = x & 3;
    if (s < 32) {
        ti = tj = s & 7;
        int c = ((s >> 3) << 2) + xr;        // 0..15
        ks0 = c * 8; diag = true;            // 8 slabs of 64 k
    } else {
        int sp = s - 32;
        int c = ((sp / 28) << 2) + xr;       // 0..31
        int tt = sp % 28;
        int a = 0;
        while (tt >= 7 - a) { tt -= 7 - a; ++a; }
        ti = a; tj = a + 1 + tt;
        ks0 = c * 4; diag = false;           // 4 slabs of 64 k
    }
}
__device__ __forceinline__ int bid_off(int m, int tt, int c) {
    return (m * 4 + (c & 3)) + ((32 + (c >> 2) * 28 + tt) << 3);
}
__device__ __forceinline__ int bid_diag(int m, int dt, int c) {
    return (m * 4 + (c & 3)) + ((((c >> 2) << 3) + dt) << 3);
}

// ---- pass 1: fp32 -> i8 (scale 32), pre-permuted chunk layout (proven r13) ----
// chunk = (m, panel p, k-slab ks of 64): 8 KB. slot t: row rl=t>>2, slot s=(t&3)^((rl>>1)&3).
__global__ __launch_bounds__(256)
void convert_kernel(const float* __restrict__ pred, const float* __restrict__ tgt,
                    char* __restrict__ q) {
    const int idx = blockIdx.x * 256 + threadIdx.x;  // 0..1048575
    const int t = idx & 511;
    const int c = idx >> 9;                           // chunk 0..2047
    const int m = c >> 10, p = (c >> 7) & 7, ks = c & 127;
    const int rl = t >> 2;
    const int s = (t & 3) ^ ((rl >> 1) & 3);
    const float* __restrict__ src = (m ? tgt : pred) + (size_t)(p * 128 + rl) * D + ks * 64 + s * 16;
    const float4 a = ((const float4*)src)[0];
    const float4 b = ((const float4*)src)[1];
    const float4 e = ((const float4*)src)[2];
    const float4 f = ((const float4*)src)[3];
    int32x4 o;
    o[0] = pack4(a.x, a.y, a.z, a.w);
    o[1] = pack4(b.x, b.y, b.z, b.w);
    o[2] = pack4(e.x, e.y, e.z, e.w);
    o[3] = pack4(f.x, f.y, f.z, f.w);
    *(int32x4*)(q + (size_t)c * 8192 + t * 16) = o;
}

// ---- pass 2: barrier-free i8 gram. Whole K-chunk in LDS (64 KB), ONE barrier:
//      issue all slabs via global_load_lds -> vmcnt(0) -> barrier -> pure ds_read+MFMA. ----
#define COMPUTE_SLAB(SS, BOFF) { \
    const char* __restrict__ bA = lsb + (SS) * 8192; \
    const char* __restrict__ bB = lsb + (BOFF) + (SS) * 8192; \
    int32x4 b0 = *(const int32x4*)(bB + rbB + kby); \
    int32x4 b1 = *(const int32x4*)(bB + rbB + 1024 + kby); \
    _Pragma("unroll") \
    for (int mi = 0; mi < 4; ++mi) { \
        int32x4 af = *(const int32x4*)(bA + rbA + mi * 1024 + kby); \
        acc[mi][0] = __builtin_amdgcn_mfma_i32_16x16x64_i8(af, b0, acc[mi][0], 0, 0, 0); \
        acc[mi][1] = __builtin_amdgcn_mfma_i32_16x16x64_i8(af, b1, acc[mi][1], 0, 0, 0); \
    } \
}

__global__ __launch_bounds__(512, 4)
void gram_kernel(const char* __restrict__ q, __half* __restrict__ part,
                 float* __restrict__ norms) {
    int m, ti, tj, ks0;
    bool diag;
    decode_bid(blockIdx.x, m, ti, tj, ks0, diag);

    __shared__ short ls[32768];      // 64 KB: diag = A[8 slabs]; off-diag = A[4] | B[4]
    char* lsb = (char*)ls;

    const int tid = threadIdx.x;
    const int lane = tid & 63;
    const int wid = tid >> 6;
    const int wr = wid >> 2, wc = wid & 3;   // 8 waves: 2x4 grid of 64x32 wave tiles

    const char* __restrict__ gAc = q + (size_t)(m * 1024 + ti * 128 + ks0) * 8192;
    const char* __restrict__ gBc = q + (size_t)(m * 1024 + tj * 128 + ks0) * 8192;
    const int gsub = wid * 1024 + lane * 16;   // per-lane src; LDS dest wave-uniform + lane*16

    const int rbA = (wr * 64 + (lane & 15)) * 64;
    const int rbB = (wc * 32 + (lane & 15)) * 64;
    const int kby = (((lane >> 4) ^ (((lane & 15) >> 1) & 3)) << 4);

    int32x4 zero = {0, 0, 0, 0};
    int32x4 acc[4][2];
#pragma unroll
    for (int mi = 0; mi < 4; ++mi) { acc[mi][0] = zero; acc[mi][1] = zero; }

    if (diag) {
#pragma unroll
        for (int ss = 0; ss < 8; ++ss)
            GLOAD_LDS(gAc + (size_t)ss * 8192 + gsub, lsb + ss * 8192 + wid * 1024);
    } else {
#pragma unroll
        for (int ss = 0; ss < 4; ++ss) {
            GLOAD_LDS(gAc + (size_t)ss * 8192 + gsub, lsb + ss * 8192 + wid * 1024);
            GLOAD_LDS(gBc + (size_t)ss * 8192 + gsub, lsb + 32768 + ss * 8192 + wid * 1024);
        }
    }
    asm volatile("s_waitcnt vmcnt(0)" ::: "memory");
    __builtin_amdgcn_s_barrier();

    __builtin_amdgcn_s_setprio(1);
    if (diag) {
#pragma unroll
        for (int ss = 0; ss < 8; ++ss) COMPUTE_SLAB(ss, 0)
    } else {
#pragma unroll
        for (int ss = 0; ss < 4; ++ss) COMPUTE_SLAB(ss, 32768)
    }
    __builtin_amdgcn_s_setprio(0);

    // epilogue: G = acc/1024 (scale 32^2) -> fp16 partials; norms from diag tiles
    __half* __restrict__ dst = part + (size_t)blockIdx.x * 16384;
#pragma unroll
    for (int mi = 0; mi < 4; ++mi)
#pragma unroll
        for (int ni = 0; ni < 2; ++ni)
#pragma unroll
            for (int r = 0; r < 4; ++r) {
                int li = wr * 64 + mi * 16 + (lane >> 4) * 4 + r;
                int lj = wc * 32 + ni * 16 + (lane & 15);
                float g = (float)acc[mi][ni][r] * (1.f / 1024.f);
                dst[li * 128 + lj] = __float2half_rn(g);
                if (diag && li == lj)
                    atomicAdd(&norms[m * 1024 + ti * 128 + li], g);
            }
}

// ---- loss: strip of 8 j per thread, fp16x8 gathers; diag 16 chunks, off-diag 32 ----
__global__ __launch_bounds__(256)
void loss_store_kernel(const __half* __restrict__ part, const float* __restrict__ norms,
                       float* __restrict__ partial) {
    const int tid = threadIdx.x;
    const int sid = blockIdx.x * 256 + tid;
    const int i  = sid >> 7;
    const int j0 = (sid & 127) << 3;
    float local = 0.f;
    if (j0 + 7 > i) {
        const int ti = i >> 7, tj = j0 >> 7;
        const int el = ((i & 127) << 7) + (j0 & 127);
        float gp[8] = {0,0,0,0,0,0,0,0}, gt[8] = {0,0,0,0,0,0,0,0};
        if (ti == tj) {
#pragma unroll
            for (int c = 0; c < 16; ++c) {
                f16x8 vp = *(const f16x8*)(part + (size_t)bid_diag(0, ti, c) * 16384 + el);
                f16x8 vt = *(const f16x8*)(part + (size_t)bid_diag(1, ti, c) * 16384 + el);
#pragma unroll
                for (int e = 0; e < 8; ++e) { gp[e] += (float)vp[e]; gt[e] += (float)vt[e]; }
            }
        } else {
            int tt = 7 * ti - (ti * (ti - 1)) / 2 + (tj - ti - 1);
#pragma unroll
            for (int c = 0; c < 32; ++c) {
                f16x8 vp = *(const f16x8*)(part + (size_t)bid_off(0, tt, c) * 16384 + el);
                f16x8 vt = *(const f16x8*)(part + (size_t)bid_off(1, tt, c) * 16384 + el);
#pragma unroll
                for (int e = 0; e < 8; ++e) { gp[e] += (float)vp[e]; gt[e] += (float)vt[e]; }
            }
        }
        const float nip = norms[i], nit = norms[1024 + i];
        const float4 njp0 = *(const float4*)(norms + j0);
        const float4 njp1 = *(const float4*)(norms + j0 + 4);
        const float4 njt0 = *(const float4*)(norms + 1024 + j0);
        const float4 njt1 = *(const float4*)(norms + 1024 + j0 + 4);
        const float njp[8] = {njp0.x, njp0.y, njp0.z, njp0.w, njp1.x, njp1.y, njp1.z, njp1.w};
        const float njt[8] = {njt0.x, njt0.y, njt0.z, njt0.w, njt1.x, njt1.y, njt1.z, njt1.w};
#pragma unroll
        for (int e = 0; e < 8; ++e) {
            int j = j0 + e;
            if (j > i) {
                float dp = nip + njp[e] - 2.f * gp[e];
                float dt = nit + njt[e] - 2.f * gt[e];
                float c2 = sqrtf(fmaxf(dp, 0.f)) - sqrtf(fmaxf(dt, 0.f));
                local += c2 * c2;
            }
        }
    }
#pragma unroll
    for (int off = 32; off > 0; off >>= 1) local += __shfl_down(local, off);
    __shared__ float wsum[4];
    if ((tid & 63) == 0) wsum[tid >> 6] = local;
    __syncthreads();
    if (tid == 0) partial[blockIdx.x] = wsum[0] + wsum[1] + wsum[2] + wsum[3];
}

template<int NPART>
__global__ __launch_bounds__(256)
void finalize_kernel(const float* __restrict__ partial, float* __restrict__ out) {
    const int tid = threadIdx.x;
    double local = 0.0;
#pragma unroll
    for (int k = 0; k < NPART / 256; ++k) local += (double)partial[tid + k * 256];
#pragma unroll
    for (int off = 32; off > 0; off >>= 1) local += __shfl_down(local, off);
    __shared__ double wsum[4];
    if ((tid & 63) == 0) wsum[tid >> 6] = local;
    __syncthreads();
    if (tid == 0) out[0] = (float)((wsum[0] + wsum[1] + wsum[2] + wsum[3]) / NPAIR);
}

// ---- fallback (small ws): reg-staged bf16 atomic-gram path (proven r11) ----
__device__ __forceinline__ void decode_bid_fb(int bid, int& m, int& ti, int& tj, int& k0, int& nsteps) {
    int x = bid & 7, s = bid >> 3;
    m = x >> 2;
    int xr = x & 3;
    if (s < 16) {
        ti = tj = s & 7;
        int c = ((s >> 3) << 2) + xr;
        k0 = c * 1024; nsteps = 32;
    } else {
        int sp = s - 16;
        int c = (sp / 28) * 4 + xr;
        int tt = sp % 28;
        int a = 0;
        while (tt >= 7 - a) { tt -= 7 - a; ++a; }
        ti = a; tj = a + 1 + tt;
        k0 = c * 512; nsteps = 16;
    }
}

__global__ __launch_bounds__(512)
void gram_fb(const float* __restrict__ pred, const float* __restrict__ tgt,
             float* __restrict__ g4) {
    int m, ti, tj, k0, nsteps;
    decode_bid_fb(blockIdx.x, m, ti, tj, k0, nsteps);
    const bool same = (ti == tj);
    const float* __restrict__ x = m ? tgt : pred;
    __shared__ short lsA[2][4096];
    __shared__ short lsB[2][4096];
    const int tid = threadIdx.x;
    const int lane = tid & 63;
    const int wid = tid >> 6;
    const int wr = wid >> 2, wc = wid & 3;
    const int srow = tid >> 2, sc8 = tid & 3;
    const float* __restrict__ gA = x + (size_t)(ti * 128 + srow) * D + k0 + sc8 * 8;
    const float* __restrict__ gB = x + (size_t)(tj * 128 + srow) * D + k0 + sc8 * 8;
    const int wby = srow * 64 + ((sc8 ^ ((srow >> 1) & 3)) << 4);
    const int rbA = (wr * 64 + (lane & 15)) * 64;
    const int rbB = (wc * 32 + (lane & 15)) * 64;
    const int kby = (((lane >> 4) ^ (((lane & 15) >> 1) & 3)) << 4);
    f32x4 zero = {0.f, 0.f, 0.f, 0.f};
    f32x4 acc[4][2];
#pragma unroll
    for (int mi = 0; mi < 4; ++mi) { acc[mi][0] = zero; acc[mi][1] = zero; }
    float4 ra0, ra1, rb0, rb1;
    { const float4* p = (const float4*)gA; ra0 = p[0]; ra1 = p[1];
      if (!same) { const float4* qq = (const float4*)gB; rb0 = qq[0]; rb1 = qq[1]; } }
    *(short8*)((char*)lsA[0] + wby) = cvt8(ra0, ra1);
    if (!same) *(short8*)((char*)lsB[0] + wby) = cvt8(rb0, rb1);
    { const float4* p = (const float4*)(gA + 32); ra0 = p[0]; ra1 = p[1];
      if (!same) { const float4* qq = (const float4*)(gB + 32); rb0 = qq[0]; rb1 = qq[1]; } }
    asm volatile("s_waitcnt lgkmcnt(0)" ::: "memory");
    __builtin_amdgcn_s_barrier();
    for (int step = 0; step < nsteps; ++step) {
        const int cur = step & 1;
        const short* __restrict__ bufA = lsA[cur];
        const short* __restrict__ bufB = same ? lsA[cur] : lsB[cur];
        short8 bf0 = *(const short8*)((const char*)bufB + (rbB + kby));
        short8 bf1 = *(const short8*)((const char*)bufB + (rbB + 1024 + kby));
#pragma unroll
        for (int mi = 0; mi < 4; ++mi) {
            short8 af = *(const short8*)((const char*)bufA + (rbA + mi * 1024 + kby));
            acc[mi][0] = __builtin_amdgcn_mfma_f32_16x16x32_bf16(af, bf0, acc[mi][0], 0, 0, 0);
            acc[mi][1] = __builtin_amdgcn_mfma_f32_16x16x32_bf16(af, bf1, acc[mi][1], 0, 0, 0);
        }
        if (step + 1 < nsteps) {
            const int nxt = cur ^ 1;
            *(short8*)((char*)lsA[nxt] + wby) = cvt8(ra0, ra1);
            if (!same) *(short8*)((char*)lsB[nxt] + wby) = cvt8(rb0, rb1);
            if (step + 2 < nsteps) {
                const float4* p = (const float4*)(gA + (step + 2) * 32);
                ra0 = p[0]; ra1 = p[1];
                if (!same) { const float4* qq = (const float4*)(gB + (step + 2) * 32); rb0 = qq[0]; rb1 = qq[1]; }
            }
        }
        asm volatile("s_waitcnt lgkmcnt(0)" ::: "memory");
        __builtin_amdgcn_s_barrier();
    }
#pragma unroll
    for (int mi = 0; mi < 4; ++mi)
#pragma unroll
        for (int ni = 0; ni < 2; ++ni)
#pragma unroll
            for (int r = 0; r < 4; ++r) {
                int gi = ti * 128 + wr * 64 + mi * 16 + (lane >> 4) * 4 + r;
                int gj = tj * 128 + wc * 32 + ni * 16 + (lane & 15);
                atomicAdd(&g4[(size_t)m * 1048576 + gi * 1024 + gj], acc[mi][ni][r]);
            }
}

__global__ __launch_bounds__(256)
void loss_atomic_kernel(const float* __restrict__ gram, float* __restrict__ partial) {
    const float* __restrict__ gP = gram;
    const float* __restrict__ gT = gram + 1024 * 1024;
    const int tid = threadIdx.x;
    const int base = blockIdx.x * 256 + tid;
    float local = 0.f;
#pragma unroll
    for (int s = 0; s < 4; ++s) {
        int lin = base + s * 262144;
        int i = lin >> 10, j = lin & 1023;
        if (j > i) {
            float dp = gP[i * 1024 + i] + gP[j * 1024 + j] - 2.f * gP[lin];
            float dt = gT[i * 1024 + i] + gT[j * 1024 + j] - 2.f * gT[lin];
            float c = sqrtf(fmaxf(dp, 0.f)) - sqrtf(fmaxf(dt, 0.f));
            local += c * c;
        }
    }
#pragma unroll
    for (int off = 32; off > 0; off >>= 1) local += __shfl_down(local, off);
    __shared__ float wsum[4];
    if ((tid & 63) == 0) wsum[tid >> 6] = local;
    __syncthreads();
    if (tid == 0) partial[blockIdx.x] = wsum[0] + wsum[1] + wsum[2] + wsum[3];
}

extern "C" void kernel_launch(void* const* d_in, const int* in_sizes, int n_in,
                              void* d_out, int out_size, void* d_ws, size_t ws_size,
                              hipStream_t stream) {
    const float* pred = (const float*)d_in[0];
    const float* tgt  = (const float*)d_in[1];
    // layout: i8 buf 16 MB | part fp16 [2048*16384] 64 MB | norms f32 2048 | partial f32 512
    const size_t q_bytes    = (size_t)2048 * 8192;
    const size_t part_bytes = (size_t)2048 * 16384 * 2;
    const size_t need = q_bytes + part_bytes + (2048 + 512) * sizeof(float);
    if (ws_size >= need) {
        char* qbuf     = (char*)d_ws;
        __half* part   = (__half*)((char*)d_ws + q_bytes);
        float* norms   = (float*)((char*)part + part_bytes);
        float* partial = norms + 2048;
        hipMemsetAsync(norms, 0, 2048 * sizeof(float), stream);
        convert_kernel<<<4096, 256, 0, stream>>>(pred, tgt, qbuf);
        gram_kernel<<<2048, 512, 0, stream>>>(qbuf, part, norms);
        loss_store_kernel<<<512, 256, 0, stream>>>(part, norms, partial);
        finalize_kernel<512><<<1, 256, 0, stream>>>(partial, (float*)d_out);
    } else {
        float* gram    = (float*)d_ws;                  // 8 MB dense
        float* partial = (float*)d_ws + (size_t)2 * 1024 * 1024;
        hipMemsetAsync(gram, 0, (size_t)2 * 1024 * 1024 * sizeof(float), stream);
        gram_fb<<<1024, 512, 0, stream>>>(pred, tgt, gram);
        loss_atomic_kernel<<<1024, 256, 0, stream>>>(gram, partial);
        finalize_kernel<1024><<<1, 256, 0, stream>>>(partial, (float*)d_out);
    }
}

// Round 16
// 48.526 us; speedup vs baseline: 1.2548x; 1.2548x over previous
//
#include <hip/hip_runtime.h>
#include <hip/hip_bf16.h>
#include <hip/hip_fp16.h>

#define D 8192
#define NPAIR 523776.0

typedef short short8 __attribute__((ext_vector_type(8)));
typedef float f32x4 __attribute__((ext_vector_type(4)));
typedef _Float16 f16x8 __attribute__((ext_vector_type(8)));
typedef int int32x4 __attribute__((ext_vector_type(4)));

#define GLOAD_LDS(G, L) __builtin_amdgcn_global_load_lds( \
    (const __attribute__((address_space(1))) void*)(G),   \
    (__attribute__((address_space(3))) void*)(L), 16, 0, 0)

__device__ __forceinline__ short8 cvt8(const float4 a, const float4 b) {
    union { short8 s; __hip_bfloat162 h[4]; } u;
    u.h[0] = __float22bfloat162_rn(make_float2(a.x, a.y));
    u.h[1] = __float22bfloat162_rn(make_float2(a.z, a.w));
    u.h[2] = __float22bfloat162_rn(make_float2(b.x, b.y));
    u.h[3] = __float22bfloat162_rn(make_float2(b.z, b.w));
    return u.s;
}

__device__ __forceinline__ int q8(float x) {
    return __float2int_rn(fminf(fmaxf(x * 32.f, -127.f), 127.f));
}
__device__ __forceinline__ int pack4(float a, float b, float c, float d) {
    return (q8(a) & 255) | ((q8(b) & 255) << 8) | ((q8(c) & 255) << 16) | ((q8(d) & 255) << 24);
}

// ---- tile decode: 1024 blocks, diag-first (BK=64 i8) ----
__device__ __forceinline__ void decode_bid(int bid, int& m, int& ti, int& tj, int& k0, int& nsteps) {
    int x = bid & 7, s = bid >> 3;
    m = x >> 2;
    int xr = x & 3;
    if (s < 16) {
        ti = tj = s & 7;
        int c = ((s >> 3) << 2) + xr;
        k0 = c * 1024; nsteps = 16;
    } else {
        int sp = s - 16;
        int c = (sp / 28) * 4 + xr;
        int tt = sp % 28;
        int a = 0;
        while (tt >= 7 - a) { tt -= 7 - a; ++a; }
        ti = a; tj = a + 1 + tt;
        k0 = c * 512; nsteps = 8;
    }
}
__device__ __forceinline__ int bid_off(int m, int tt, int c) {
    return (m * 4 + (c & 3)) + ((16 + (c >> 2) * 28 + tt) << 3);
}
__device__ __forceinline__ int bid_diag(int m, int dt, int c) {
    return (m * 4 + (c & 3)) + ((((c >> 2) << 3) + dt) << 3);
}

// ---- pass 1: fp32 -> i8 (scale 32), pre-permuted chunk layout (proven r13) ----
__global__ __launch_bounds__(256)
void convert_kernel(const float* __restrict__ pred, const float* __restrict__ tgt,
                    char* __restrict__ q) {
    const int idx = blockIdx.x * 256 + threadIdx.x;  // 0..1048575
    const int t = idx & 511;
    const int c = idx >> 9;                           // chunk 0..2047
    const int m = c >> 10, p = (c >> 7) & 7, ks = c & 127;
    const int rl = t >> 2;
    const int s = (t & 3) ^ ((rl >> 1) & 3);
    const float* __restrict__ src = (m ? tgt : pred) + (size_t)(p * 128 + rl) * D + ks * 64 + s * 16;
    const float4 a = ((const float4*)src)[0];
    const float4 b = ((const float4*)src)[1];
    const float4 e = ((const float4*)src)[2];
    const float4 f = ((const float4*)src)[3];
    int32x4 o;
    o[0] = pack4(a.x, a.y, a.z, a.w);
    o[1] = pack4(b.x, b.y, b.z, b.w);
    o[2] = pack4(e.x, e.y, e.z, e.w);
    o[3] = pack4(f.x, f.y, f.z, f.w);
    *(int32x4*)(q + (size_t)c * 8192 + t * 16) = o;
}

// ---- pass 2: i8 gram, 2 LDS buffer sets (32 KB -> 4 blocks/CU, full 32-wave occ),
//      2-phase: STAGE(S+1) -> MFMA(S) -> vmcnt(0)+barrier (T3 minimum recipe) ----
#define STAGE(S, COFF) { \
    GLOAD_LDS(gAc + (size_t)(S) * 8192 + gsub, lsb + (COFF) + wid * 1024); \
    if (!same) GLOAD_LDS(gBc + (size_t)(S) * 8192 + gsub, lsb + (COFF) + 8192 + wid * 1024); \
}

#define GSTEP { \
    if (sp + 1 < nsteps) STAGE(sp + 1, cN); \
    { \
        const char* __restrict__ bA = lsb + cC; \
        const char* __restrict__ bB = lsb + cC + boff; \
        __builtin_amdgcn_s_setprio(1); \
        int32x4 b0 = *(const int32x4*)(bB + rbB + kby); \
        int32x4 b1 = *(const int32x4*)(bB + rbB + 1024 + kby); \
        _Pragma("unroll") \
        for (int mi = 0; mi < 4; ++mi) { \
            int32x4 af = *(const int32x4*)(bA + rbA + mi * 1024 + kby); \
            acc[mi][0] = __builtin_amdgcn_mfma_i32_16x16x64_i8(af, b0, acc[mi][0], 0, 0, 0); \
            acc[mi][1] = __builtin_amdgcn_mfma_i32_16x16x64_i8(af, b1, acc[mi][1], 0, 0, 0); \
        } \
        __builtin_amdgcn_s_setprio(0); \
    } \
    asm volatile("s_waitcnt vmcnt(0)" ::: "memory"); \
    __builtin_amdgcn_s_barrier(); \
    { int t_ = cC; cC = cN; cN = t_; } \
    ++sp; \
}

__global__ __launch_bounds__(512, 4)
void gram_kernel(const char* __restrict__ q, __half* __restrict__ part,
                 float* __restrict__ norms) {
    int m, ti, tj, k0, nsteps;
    decode_bid(blockIdx.x, m, ti, tj, k0, nsteps);
    const bool same = (ti == tj);

    __shared__ short ls[16384];      // 2 sets x (A 8 KB + B 8 KB) = 32 KB
    char* lsb = (char*)ls;

    const int tid = threadIdx.x;
    const int lane = tid & 63;
    const int wid = tid >> 6;
    const int wr = wid >> 2, wc = wid & 3;   // 8 waves: 2x4 grid of 64x32 wave tiles

    const char* __restrict__ gAc = q + (size_t)(m * 1024 + ti * 128 + (k0 >> 6)) * 8192;
    const char* __restrict__ gBc = q + (size_t)(m * 1024 + tj * 128 + (k0 >> 6)) * 8192;
    const int gsub = wid * 1024 + lane * 16;   // per-lane source; LDS dest wave-uniform

    const int boff = same ? 0 : 8192;
    const int rbA = (wr * 64 + (lane & 15)) * 64;
    const int rbB = (wc * 32 + (lane & 15)) * 64;
    const int kby = (((lane >> 4) ^ (((lane & 15) >> 1) & 3)) << 4);

    int32x4 zero = {0, 0, 0, 0};
    int32x4 acc[4][2];
#pragma unroll
    for (int mi = 0; mi < 4; ++mi) { acc[mi][0] = zero; acc[mi][1] = zero; }

    int cC = 0, cN = 16384;

    STAGE(0, cC)
    asm volatile("s_waitcnt vmcnt(0)" ::: "memory");
    __builtin_amdgcn_s_barrier();

    int sp = 0;
    while (sp < nsteps) { GSTEP }

    // epilogue: G = acc/1024 (scale 32^2) -> fp16 partials; norms from diag tiles
    __half* __restrict__ dst = part + (size_t)blockIdx.x * 16384;
#pragma unroll
    for (int mi = 0; mi < 4; ++mi)
#pragma unroll
        for (int ni = 0; ni < 2; ++ni)
#pragma unroll
            for (int r = 0; r < 4; ++r) {
                int li = wr * 64 + mi * 16 + (lane >> 4) * 4 + r;
                int lj = wc * 32 + ni * 16 + (lane & 15);
                float g = (float)acc[mi][ni][r] * (1.f / 1024.f);
                dst[li * 128 + lj] = __float2half_rn(g);
                if (same && li == lj)
                    atomicAdd(&norms[m * 1024 + ti * 128 + li], g);
            }
}

// ---- loss (r11 strip version, proven) ----
__global__ __launch_bounds__(256)
void loss_store_kernel(const __half* __restrict__ part, const float* __restrict__ norms,
                       float* __restrict__ partial) {
    const int tid = threadIdx.x;
    const int sid = blockIdx.x * 256 + tid;
    const int i  = sid >> 7;
    const int j0 = (sid & 127) << 3;
    float local = 0.f;
    if (j0 + 7 > i) {
        const int ti = i >> 7, tj = j0 >> 7;
        const int el = ((i & 127) << 7) + (j0 & 127);
        float gp[8] = {0,0,0,0,0,0,0,0}, gt[8] = {0,0,0,0,0,0,0,0};
        if (ti == tj) {
#pragma unroll
            for (int c = 0; c < 8; ++c) {
                f16x8 vp = *(const f16x8*)(part + (size_t)bid_diag(0, ti, c) * 16384 + el);
                f16x8 vt = *(const f16x8*)(part + (size_t)bid_diag(1, ti, c) * 16384 + el);
#pragma unroll
                for (int e = 0; e < 8; ++e) { gp[e] += (float)vp[e]; gt[e] += (float)vt[e]; }
            }
        } else {
            int tt = 7 * ti - (ti * (ti - 1)) / 2 + (tj - ti - 1);
#pragma unroll
            for (int c = 0; c < 16; ++c) {
                f16x8 vp = *(const f16x8*)(part + (size_t)bid_off(0, tt, c) * 16384 + el);
                f16x8 vt = *(const f16x8*)(part + (size_t)bid_off(1, tt, c) * 16384 + el);
#pragma unroll
                for (int e = 0; e < 8; ++e) { gp[e] += (float)vp[e]; gt[e] += (float)vt[e]; }
            }
        }
        const float nip = norms[i], nit = norms[1024 + i];
        const float4 njp0 = *(const float4*)(norms + j0);
        const float4 njp1 = *(const float4*)(norms + j0 + 4);
        const float4 njt0 = *(const float4*)(norms + 1024 + j0);
        const float4 njt1 = *(const float4*)(norms + 1024 + j0 + 4);
        const float njp[8] = {njp0.x, njp0.y, njp0.z, njp0.w, njp1.x, njp1.y, njp1.z, njp1.w};
        const float njt[8] = {njt0.x, njt0.y, njt0.z, njt0.w, njt1.x, njt1.y, njt1.z, njt1.w};
#pragma unroll
        for (int e = 0; e < 8; ++e) {
            int j = j0 + e;
            if (j > i) {
                float dp = nip + njp[e] - 2.f * gp[e];
                float dt = nit + njt[e] - 2.f * gt[e];
                float c2 = sqrtf(fmaxf(dp, 0.f)) - sqrtf(fmaxf(dt, 0.f));
                local += c2 * c2;
            }
        }
    }
#pragma unroll
    for (int off = 32; off > 0; off >>= 1) local += __shfl_down(local, off);
    __shared__ float wsum[4];
    if ((tid & 63) == 0) wsum[tid >> 6] = local;
    __syncthreads();
    if (tid == 0) partial[blockIdx.x] = wsum[0] + wsum[1] + wsum[2] + wsum[3];
}

template<int NPART>
__global__ __launch_bounds__(256)
void finalize_kernel(const float* __restrict__ partial, float* __restrict__ out) {
    const int tid = threadIdx.x;
    double local = 0.0;
#pragma unroll
    for (int k = 0; k < NPART / 256; ++k) local += (double)partial[tid + k * 256];
#pragma unroll
    for (int off = 32; off > 0; off >>= 1) local += __shfl_down(local, off);
    __shared__ double wsum[4];
    if ((tid & 63) == 0) wsum[tid >> 6] = local;
    __syncthreads();
    if (tid == 0) out[0] = (float)((wsum[0] + wsum[1] + wsum[2] + wsum[3]) / NPAIR);
}

// ---- fallback (small ws): reg-staged bf16 atomic-gram path (proven r11) ----
__device__ __forceinline__ void decode_bid_fb(int bid, int& m, int& ti, int& tj, int& k0, int& nsteps) {
    int x = bid & 7, s = bid >> 3;
    m = x >> 2;
    int xr = x & 3;
    if (s < 16) {
        ti = tj = s & 7;
        int c = ((s >> 3) << 2) + xr;
        k0 = c * 1024; nsteps = 32;
    } else {
        int sp = s - 16;
        int c = (sp / 28) * 4 + xr;
        int tt = sp % 28;
        int a = 0;
        while (tt >= 7 - a) { tt -= 7 - a; ++a; }
        ti = a; tj = a + 1 + tt;
        k0 = c * 512; nsteps = 16;
    }
}

__global__ __launch_bounds__(512)
void gram_fb(const float* __restrict__ pred, const float* __restrict__ tgt,
             float* __restrict__ g4) {
    int m, ti, tj, k0, nsteps;
    decode_bid_fb(blockIdx.x, m, ti, tj, k0, nsteps);
    const bool same = (ti == tj);
    const float* __restrict__ x = m ? tgt : pred;
    __shared__ short lsA[2][4096];
    __shared__ short lsB[2][4096];
    const int tid = threadIdx.x;
    const int lane = tid & 63;
    const int wid = tid >> 6;
    const int wr = wid >> 2, wc = wid & 3;
    const int srow = tid >> 2, sc8 = tid & 3;
    const float* __restrict__ gA = x + (size_t)(ti * 128 + srow) * D + k0 + sc8 * 8;
    const float* __restrict__ gB = x + (size_t)(tj * 128 + srow) * D + k0 + sc8 * 8;
    const int wby = srow * 64 + ((sc8 ^ ((srow >> 1) & 3)) << 4);
    const int rbA = (wr * 64 + (lane & 15)) * 64;
    const int rbB = (wc * 32 + (lane & 15)) * 64;
    const int kby = (((lane >> 4) ^ (((lane & 15) >> 1) & 3)) << 4);
    f32x4 zero = {0.f, 0.f, 0.f, 0.f};
    f32x4 acc[4][2];
#pragma unroll
    for (int mi = 0; mi < 4; ++mi) { acc[mi][0] = zero; acc[mi][1] = zero; }
    float4 ra0, ra1, rb0, rb1;
    { const float4* p = (const float4*)gA; ra0 = p[0]; ra1 = p[1];
      if (!same) { const float4* qq = (const float4*)gB; rb0 = qq[0]; rb1 = qq[1]; } }
    *(short8*)((char*)lsA[0] + wby) = cvt8(ra0, ra1);
    if (!same) *(short8*)((char*)lsB[0] + wby) = cvt8(rb0, rb1);
    { const float4* p = (const float4*)(gA + 32); ra0 = p[0]; ra1 = p[1];
      if (!same) { const float4* qq = (const float4*)(gB + 32); rb0 = qq[0]; rb1 = qq[1]; } }
    asm volatile("s_waitcnt lgkmcnt(0)" ::: "memory");
    __builtin_amdgcn_s_barrier();
    for (int step = 0; step < nsteps; ++step) {
        const int cur = step & 1;
        const short* __restrict__ bufA = lsA[cur];
        const short* __restrict__ bufB = same ? lsA[cur] : lsB[cur];
        short8 bf0 = *(const short8*)((const char*)bufB + (rbB + kby));
        short8 bf1 = *(const short8*)((const char*)bufB + (rbB + 1024 + kby));
#pragma unroll
        for (int mi = 0; mi < 4; ++mi) {
            short8 af = *(const short8*)((const char*)bufA + (rbA + mi * 1024 + kby));
            acc[mi][0] = __builtin_amdgcn_mfma_f32_16x16x32_bf16(af, bf0, acc[mi][0], 0, 0, 0);
            acc[mi][1] = __builtin_amdgcn_mfma_f32_16x16x32_bf16(af, bf1, acc[mi][1], 0, 0, 0);
        }
        if (step + 1 < nsteps) {
            const int nxt = cur ^ 1;
            *(short8*)((char*)lsA[nxt] + wby) = cvt8(ra0, ra1);
            if (!same) *(short8*)((char*)lsB[nxt] + wby) = cvt8(rb0, rb1);
            if (step + 2 < nsteps) {
                const float4* p = (const float4*)(gA + (step + 2) * 32);
                ra0 = p[0]; ra1 = p[1];
                if (!same) { const float4* qq = (const float4*)(gB + (step + 2) * 32); rb0 = qq[0]; rb1 = qq[1]; }
            }
        }
        asm volatile("s_waitcnt lgkmcnt(0)" ::: "memory");
        __builtin_amdgcn_s_barrier();
    }
#pragma unroll
    for (int mi = 0; mi < 4; ++mi)
#pragma unroll
        for (int ni = 0; ni < 2; ++ni)
#pragma unroll
            for (int r = 0; r < 4; ++r) {
                int gi = ti * 128 + wr * 64 + mi * 16 + (lane >> 4) * 4 + r;
                int gj = tj * 128 + wc * 32 + ni * 16 + (lane & 15);
                atomicAdd(&g4[(size_t)m * 1048576 + gi * 1024 + gj], acc[mi][ni][r]);
            }
}

__global__ __launch_bounds__(256)
void loss_atomic_kernel(const float* __restrict__ gram, float* __restrict__ partial) {
    const float* __restrict__ gP = gram;
    const float* __restrict__ gT = gram + 1024 * 1024;
    const int tid = threadIdx.x;
    const int base = blockIdx.x * 256 + tid;
    float local = 0.f;
#pragma unroll
    for (int s = 0; s < 4; ++s) {
        int lin = base + s * 262144;
        int i = lin >> 10, j = lin & 1023;
        if (j > i) {
            float dp = gP[i * 1024 + i] + gP[j * 1024 + j] - 2.f * gP[lin];
            float dt = gT[i * 1024 + i] + gT[j * 1024 + j] - 2.f * gT[lin];
            float c = sqrtf(fmaxf(dp, 0.f)) - sqrtf(fmaxf(dt, 0.f));
            local += c * c;
        }
    }
#pragma unroll
    for (int off = 32; off > 0; off >>= 1) local += __shfl_down(local, off);
    __shared__ float wsum[4];
    if ((tid & 63) == 0) wsum[tid >> 6] = local;
    __syncthreads();
    if (tid == 0) partial[blockIdx.x] = wsum[0] + wsum[1] + wsum[2] + wsum[3];
}

extern "C" void kernel_launch(void* const* d_in, const int* in_sizes, int n_in,
                              void* d_out, int out_size, void* d_ws, size_t ws_size,
                              hipStream_t stream) {
    const float* pred = (const float*)d_in[0];
    const float* tgt  = (const float*)d_in[1];
    // layout: i8 buf [2048*8192 B] 16 MB | part fp16 33.5 MB | norms f32 2048 | partial f32 512
    const size_t q_bytes    = (size_t)2048 * 8192;
    const size_t part_bytes = (size_t)1024 * 16384 * 2;
    const size_t need = q_bytes + part_bytes + (2048 + 512) * sizeof(float);
    if (ws_size >= need) {
        char* qbuf     = (char*)d_ws;
        __half* part   = (__half*)((char*)d_ws + q_bytes);
        float* norms   = (float*)((char*)part + part_bytes);
        float* partial = norms + 2048;
        hipMemsetAsync(norms, 0, 2048 * sizeof(float), stream);
        convert_kernel<<<4096, 256, 0, stream>>>(pred, tgt, qbuf);
        gram_kernel<<<1024, 512, 0, stream>>>(qbuf, part, norms);
        loss_store_kernel<<<512, 256, 0, stream>>>(part, norms, partial);
        finalize_kernel<512><<<1, 256, 0, stream>>>(partial, (float*)d_out);
    } else {
        float* gram    = (float*)d_ws;                  // 8 MB dense
        float* partial = (float*)d_ws + (size_t)2 * 1024 * 1024;
        hipMemsetAsync(gram, 0, (size_t)2 * 1024 * 1024 * sizeof(float), stream);
        gram_fb<<<1024, 512, 0, stream>>>(pred, tgt, gram);
        loss_atomic_kernel<<<1024, 256, 0, stream>>>(gram, partial);
        finalize_kernel<1024><<<1, 256, 0, stream>>>(partial, (float*)d_out);
    }
}

// Round 17
// 47.863 us; speedup vs baseline: 1.2721x; 1.0138x over previous
//
#include <hip/hip_runtime.h>
#include <hip/hip_bf16.h>
#include <hip/hip_fp16.h>

#define D 8192
#define NPAIR 523776.0

typedef short short8 __attribute__((ext_vector_type(8)));
typedef float f32x4 __attribute__((ext_vector_type(4)));
typedef _Float16 f16x8 __attribute__((ext_vector_type(8)));
typedef int int32x4 __attribute__((ext_vector_type(4)));

#define GLOAD_LDS(G, L) __builtin_amdgcn_global_load_lds( \
    (const __attribute__((address_space(1))) void*)(G),   \
    (__attribute__((address_space(3))) void*)(L), 16, 0, 0)

__device__ __forceinline__ short8 cvt8(const float4 a, const float4 b) {
    union { short8 s; __hip_bfloat162 h[4]; } u;
    u.h[0] = __float22bfloat162_rn(make_float2(a.x, a.y));
    u.h[1] = __float22bfloat162_rn(make_float2(a.z, a.w));
    u.h[2] = __float22bfloat162_rn(make_float2(b.x, b.y));
    u.h[3] = __float22bfloat162_rn(make_float2(b.z, b.w));
    return u.s;
}

__device__ __forceinline__ int q8(float x) {
    return __float2int_rn(fminf(fmaxf(x * 32.f, -127.f), 127.f));
}
__device__ __forceinline__ int pack4(float a, float b, float c, float d) {
    return (q8(a) & 255) | ((q8(b) & 255) << 8) | ((q8(c) & 255) << 16) | ((q8(d) & 255) << 24);
}

// ---- tile decode: 1024 blocks, diag-first (BK=64 i8) ----
__device__ __forceinline__ void decode_bid(int bid, int& m, int& ti, int& tj, int& k0, int& nsteps) {
    int x = bid & 7, s = bid >> 3;
    m = x >> 2;
    int xr = x & 3;
    if (s < 16) {
        ti = tj = s & 7;
        int c = ((s >> 3) << 2) + xr;
        k0 = c * 1024; nsteps = 16;
    } else {
        int sp = s - 16;
        int c = (sp / 28) * 4 + xr;
        int tt = sp % 28;
        int a = 0;
        while (tt >= 7 - a) { tt -= 7 - a; ++a; }
        ti = a; tj = a + 1 + tt;
        k0 = c * 512; nsteps = 8;
    }
}
__device__ __forceinline__ int bid_off(int m, int tt, int c) {
    return (m * 4 + (c & 3)) + ((16 + (c >> 2) * 28 + tt) << 3);
}
__device__ __forceinline__ int bid_diag(int m, int dt, int c) {
    return (m * 4 + (c & 3)) + ((((c >> 2) << 3) + dt) << 3);
}

// ---- pass 1: fp32 -> i8 (scale 32), pre-permuted chunk layout (proven r13) ----
__global__ __launch_bounds__(256)
void convert_kernel(const float* __restrict__ pred, const float* __restrict__ tgt,
                    char* __restrict__ q) {
    const int idx = blockIdx.x * 256 + threadIdx.x;  // 0..1048575
    const int t = idx & 511;
    const int c = idx >> 9;                           // chunk 0..2047
    const int m = c >> 10, p = (c >> 7) & 7, ks = c & 127;
    const int rl = t >> 2;
    const int s = (t & 3) ^ ((rl >> 1) & 3);
    const float* __restrict__ src = (m ? tgt : pred) + (size_t)(p * 128 + rl) * D + ks * 64 + s * 16;
    const float4 a = ((const float4*)src)[0];
    const float4 b = ((const float4*)src)[1];
    const float4 e = ((const float4*)src)[2];
    const float4 f = ((const float4*)src)[3];
    int32x4 o;
    o[0] = pack4(a.x, a.y, a.z, a.w);
    o[1] = pack4(b.x, b.y, b.z, b.w);
    o[2] = pack4(e.x, e.y, e.z, e.w);
    o[3] = pack4(f.x, f.y, f.z, f.w);
    *(int32x4*)(q + (size_t)c * 8192 + t * 16) = o;
}

// ---- pass 2: i8 gram, 2 LDS buffer sets (32 KB -> 4 blocks/CU, full 32-wave occ),
//      2-phase: STAGE(S+1) -> MFMA(S) -> vmcnt(0)+barrier (T3 minimum recipe) ----
#define STAGE(S, COFF) { \
    GLOAD_LDS(gAc + (size_t)(S) * 8192 + gsub, lsb + (COFF) + wid * 1024); \
    if (!same) GLOAD_LDS(gBc + (size_t)(S) * 8192 + gsub, lsb + (COFF) + 8192 + wid * 1024); \
}

#define GSTEP { \
    if (sp + 1 < nsteps) STAGE(sp + 1, cN); \
    { \
        const char* __restrict__ bA = lsb + cC; \
        const char* __restrict__ bB = lsb + cC + boff; \
        __builtin_amdgcn_s_setprio(1); \
        int32x4 b0 = *(const int32x4*)(bB + rbB + kby); \
        int32x4 b1 = *(const int32x4*)(bB + rbB + 1024 + kby); \
        _Pragma("unroll") \
        for (int mi = 0; mi < 4; ++mi) { \
            int32x4 af = *(const int32x4*)(bA + rbA + mi * 1024 + kby); \
            acc[mi][0] = __builtin_amdgcn_mfma_i32_16x16x64_i8(af, b0, acc[mi][0], 0, 0, 0); \
            acc[mi][1] = __builtin_amdgcn_mfma_i32_16x16x64_i8(af, b1, acc[mi][1], 0, 0, 0); \
        } \
        __builtin_amdgcn_s_setprio(0); \
    } \
    asm volatile("s_waitcnt vmcnt(0)" ::: "memory"); \
    __builtin_amdgcn_s_barrier(); \
    { int t_ = cC; cC = cN; cN = t_; } \
    ++sp; \
}

__global__ __launch_bounds__(512, 8)
void gram_kernel(const char* __restrict__ q, __half* __restrict__ part,
                 float* __restrict__ norms) {
    int m, ti, tj, k0, nsteps;
    decode_bid(blockIdx.x, m, ti, tj, k0, nsteps);
    const bool same = (ti == tj);

    __shared__ short ls[16384];      // 2 sets x (A 8 KB + B 8 KB) = 32 KB
    char* lsb = (char*)ls;

    const int tid = threadIdx.x;
    const int lane = tid & 63;
    const int wid = tid >> 6;
    const int wr = wid >> 2, wc = wid & 3;   // 8 waves: 2x4 grid of 64x32 wave tiles

    const char* __restrict__ gAc = q + (size_t)(m * 1024 + ti * 128 + (k0 >> 6)) * 8192;
    const char* __restrict__ gBc = q + (size_t)(m * 1024 + tj * 128 + (k0 >> 6)) * 8192;
    const int gsub = wid * 1024 + lane * 16;   // per-lane source; LDS dest wave-uniform

    const int boff = same ? 0 : 8192;
    const int rbA = (wr * 64 + (lane & 15)) * 64;
    const int rbB = (wc * 32 + (lane & 15)) * 64;
    const int kby = (((lane >> 4) ^ (((lane & 15) >> 1) & 3)) << 4);

    int32x4 zero = {0, 0, 0, 0};
    int32x4 acc[4][2];
#pragma unroll
    for (int mi = 0; mi < 4; ++mi) { acc[mi][0] = zero; acc[mi][1] = zero; }

    int cC = 0, cN = 16384;

    STAGE(0, cC)
    asm volatile("s_waitcnt vmcnt(0)" ::: "memory");
    __builtin_amdgcn_s_barrier();

    int sp = 0;
    while (sp < nsteps) { GSTEP }

    // ---- epilogue: G = acc/1024 -> fp16, vectorized C-write via LDS transpose ----
    // norms from diag-tile diagonals (fp32, from acc directly)
    if (same) {
#pragma unroll
        for (int mi = 0; mi < 4; ++mi)
#pragma unroll
            for (int ni = 0; ni < 2; ++ni)
#pragma unroll
                for (int r = 0; r < 4; ++r) {
                    int li = wr * 64 + mi * 16 + (lane >> 4) * 4 + r;
                    int lj = wc * 32 + ni * 16 + (lane & 15);
                    if (li == lj)
                        atomicAdd(&norms[m * 1024 + ti * 128 + li],
                                  (float)acc[mi][ni][r] * (1.f / 1024.f));
                }
    }
    __syncthreads();   // all K-loop LDS reads done; buffers now reusable as [128][128] fp16
#pragma unroll
    for (int mi = 0; mi < 4; ++mi)
#pragma unroll
        for (int ni = 0; ni < 2; ++ni)
#pragma unroll
            for (int r = 0; r < 4; ++r) {
                int li = wr * 64 + mi * 16 + (lane >> 4) * 4 + r;
                int lj = wc * 32 + ni * 16 + (lane & 15);
                int byte = li * 256 + ((lj * 2) ^ ((li & 7) << 4));   // XOR-swizzled row
                *(__half*)(lsb + byte) = __float2half_rn((float)acc[mi][ni][r] * (1.f / 1024.f));
            }
    __syncthreads();
    // coalesced readback + store: per qq, wave writes 1 KB contiguous (16 B/lane)
    char* __restrict__ dstb = (char*)(part + (size_t)blockIdx.x * 16384);
#pragma unroll
    for (int qq = 0; qq < 4; ++qq) {
        int L = qq * 8192 + tid * 16;              // logical byte offset in tile
        int li = L >> 8;
        f16x8 v = *(const f16x8*)(lsb + (L ^ ((li & 7) << 4)));
        *(f16x8*)(dstb + L) = v;
    }
}

// ---- loss (r11 strip version, proven) ----
__global__ __launch_bounds__(256)
void loss_store_kernel(const __half* __restrict__ part, const float* __restrict__ norms,
                       float* __restrict__ partial) {
    const int tid = threadIdx.x;
    const int sid = blockIdx.x * 256 + tid;
    const int i  = sid >> 7;
    const int j0 = (sid & 127) << 3;
    float local = 0.f;
    if (j0 + 7 > i) {
        const int ti = i >> 7, tj = j0 >> 7;
        const int el = ((i & 127) << 7) + (j0 & 127);
        float gp[8] = {0,0,0,0,0,0,0,0}, gt[8] = {0,0,0,0,0,0,0,0};
        if (ti == tj) {
#pragma unroll
            for (int c = 0; c < 8; ++c) {
                f16x8 vp = *(const f16x8*)(part + (size_t)bid_diag(0, ti, c) * 16384 + el);
                f16x8 vt = *(const f16x8*)(part + (size_t)bid_diag(1, ti, c) * 16384 + el);
#pragma unroll
                for (int e = 0; e < 8; ++e) { gp[e] += (float)vp[e]; gt[e] += (float)vt[e]; }
            }
        } else {
            int tt = 7 * ti - (ti * (ti - 1)) / 2 + (tj - ti - 1);
#pragma unroll
            for (int c = 0; c < 16; ++c) {
                f16x8 vp = *(const f16x8*)(part + (size_t)bid_off(0, tt, c) * 16384 + el);
                f16x8 vt = *(const f16x8*)(part + (size_t)bid_off(1, tt, c) * 16384 + el);
#pragma unroll
                for (int e = 0; e < 8; ++e) { gp[e] += (float)vp[e]; gt[e] += (float)vt[e]; }
            }
        }
        const float nip = norms[i], nit = norms[1024 + i];
        const float4 njp0 = *(const float4*)(norms + j0);
        const float4 njp1 = *(const float4*)(norms + j0 + 4);
        const float4 njt0 = *(const float4*)(norms + 1024 + j0);
        const float4 njt1 = *(const float4*)(norms + 1024 + j0 + 4);
        const float njp[8] = {njp0.x, njp0.y, njp0.z, njp0.w, njp1.x, njp1.y, njp1.z, njp1.w};
        const float njt[8] = {njt0.x, njt0.y, njt0.z, njt0.w, njt1.x, njt1.y, njt1.z, njt1.w};
#pragma unroll
        for (int e = 0; e < 8; ++e) {
            int j = j0 + e;
            if (j > i) {
                float dp = nip + njp[e] - 2.f * gp[e];
                float dt = nit + njt[e] - 2.f * gt[e];
                float c2 = sqrtf(fmaxf(dp, 0.f)) - sqrtf(fmaxf(dt, 0.f));
                local += c2 * c2;
            }
        }
    }
#pragma unroll
    for (int off = 32; off > 0; off >>= 1) local += __shfl_down(local, off);
    __shared__ float wsum[4];
    if ((tid & 63) == 0) wsum[tid >> 6] = local;
    __syncthreads();
    if (tid == 0) partial[blockIdx.x] = wsum[0] + wsum[1] + wsum[2] + wsum[3];
}

template<int NPART>
__global__ __launch_bounds__(256)
void finalize_kernel(const float* __restrict__ partial, float* __restrict__ out) {
    const int tid = threadIdx.x;
    double local = 0.0;
#pragma unroll
    for (int k = 0; k < NPART / 256; ++k) local += (double)partial[tid + k * 256];
#pragma unroll
    for (int off = 32; off > 0; off >>= 1) local += __shfl_down(local, off);
    __shared__ double wsum[4];
    if ((tid & 63) == 0) wsum[tid >> 6] = local;
    __syncthreads();
    if (tid == 0) out[0] = (float)((wsum[0] + wsum[1] + wsum[2] + wsum[3]) / NPAIR);
}

// ---- fallback (small ws): reg-staged bf16 atomic-gram path (proven r11) ----
__device__ __forceinline__ void decode_bid_fb(int bid, int& m, int& ti, int& tj, int& k0, int& nsteps) {
    int x = bid & 7, s = bid >> 3;
    m = x >> 2;
    int xr = x & 3;
    if (s < 16) {
        ti = tj = s & 7;
        int c = ((s >> 3) << 2) + xr;
        k0 = c * 1024; nsteps = 32;
    } else {
        int sp = s - 16;
        int c = (sp / 28) * 4 + xr;
        int tt = sp % 28;
        int a = 0;
        while (tt >= 7 - a) { tt -= 7 - a; ++a; }
        ti = a; tj = a + 1 + tt;
        k0 = c * 512; nsteps = 16;
    }
}

__global__ __launch_bounds__(512)
void gram_fb(const float* __restrict__ pred, const float* __restrict__ tgt,
             float* __restrict__ g4) {
    int m, ti, tj, k0, nsteps;
    decode_bid_fb(blockIdx.x, m, ti, tj, k0, nsteps);
    const bool same = (ti == tj);
    const float* __restrict__ x = m ? tgt : pred;
    __shared__ short lsA[2][4096];
    __shared__ short lsB[2][4096];
    const int tid = threadIdx.x;
    const int lane = tid & 63;
    const int wid = tid >> 6;
    const int wr = wid >> 2, wc = wid & 3;
    const int srow = tid >> 2, sc8 = tid & 3;
    const float* __restrict__ gA = x + (size_t)(ti * 128 + srow) * D + k0 + sc8 * 8;
    const float* __restrict__ gB = x + (size_t)(tj * 128 + srow) * D + k0 + sc8 * 8;
    const int wby = srow * 64 + ((sc8 ^ ((srow >> 1) & 3)) << 4);
    const int rbA = (wr * 64 + (lane & 15)) * 64;
    const int rbB = (wc * 32 + (lane & 15)) * 64;
    const int kby = (((lane >> 4) ^ (((lane & 15) >> 1) & 3)) << 4);
    f32x4 zero = {0.f, 0.f, 0.f, 0.f};
    f32x4 acc[4][2];
#pragma unroll
    for (int mi = 0; mi < 4; ++mi) { acc[mi][0] = zero; acc[mi][1] = zero; }
    float4 ra0, ra1, rb0, rb1;
    { const float4* p = (const float4*)gA; ra0 = p[0]; ra1 = p[1];
      if (!same) { const float4* qq = (const float4*)gB; rb0 = qq[0]; rb1 = qq[1]; } }
    *(short8*)((char*)lsA[0] + wby) = cvt8(ra0, ra1);
    if (!same) *(short8*)((char*)lsB[0] + wby) = cvt8(rb0, rb1);
    { const float4* p = (const float4*)(gA + 32); ra0 = p[0]; ra1 = p[1];
      if (!same) { const float4* qq = (const float4*)(gB + 32); rb0 = qq[0]; rb1 = qq[1]; } }
    asm volatile("s_waitcnt lgkmcnt(0)" ::: "memory");
    __builtin_amdgcn_s_barrier();
    for (int step = 0; step < nsteps; ++step) {
        const int cur = step & 1;
        const short* __restrict__ bufA = lsA[cur];
        const short* __restrict__ bufB = same ? lsA[cur] : lsB[cur];
        short8 bf0 = *(const short8*)((const char*)bufB + (rbB + kby));
        short8 bf1 = *(const short8*)((const char*)bufB + (rbB + 1024 + kby));
#pragma unroll
        for (int mi = 0; mi < 4; ++mi) {
            short8 af = *(const short8*)((const char*)bufA + (rbA + mi * 1024 + kby));
            acc[mi][0] = __builtin_amdgcn_mfma_f32_16x16x32_bf16(af, bf0, acc[mi][0], 0, 0, 0);
            acc[mi][1] = __builtin_amdgcn_mfma_f32_16x16x32_bf16(af, bf1, acc[mi][1], 0, 0, 0);
        }
        if (step + 1 < nsteps) {
            const int nxt = cur ^ 1;
            *(short8*)((char*)lsA[nxt] + wby) = cvt8(ra0, ra1);
            if (!same) *(short8*)((char*)lsB[nxt] + wby) = cvt8(rb0, rb1);
            if (step + 2 < nsteps) {
                const float4* p = (const float4*)(gA + (step + 2) * 32);
                ra0 = p[0]; ra1 = p[1];
                if (!same) { const float4* qq = (const float4*)(gB + (step + 2) * 32); rb0 = qq[0]; rb1 = qq[1]; }
            }
        }
        asm volatile("s_waitcnt lgkmcnt(0)" ::: "memory");
        __builtin_amdgcn_s_barrier();
    }
#pragma unroll
    for (int mi = 0; mi < 4; ++mi)
#pragma unroll
        for (int ni = 0; ni < 2; ++ni)
#pragma unroll
            for (int r = 0; r < 4; ++r) {
                int gi = ti * 128 + wr * 64 + mi * 16 + (lane >> 4) * 4 + r;
                int gj = tj * 128 + wc * 32 + ni * 16 + (lane & 15);
                atomicAdd(&g4[(size_t)m * 1048576 + gi * 1024 + gj], acc[mi][ni][r]);
            }
}

__global__ __launch_bounds__(256)
void loss_atomic_kernel(const float* __restrict__ gram, float* __restrict__ partial) {
    const float* __restrict__ gP = gram;
    const float* __restrict__ gT = gram + 1024 * 1024;
    const int tid = threadIdx.x;
    const int base = blockIdx.x * 256 + tid;
    float local = 0.f;
#pragma unroll
    for (int s = 0; s < 4; ++s) {
        int lin = base + s * 262144;
        int i = lin >> 10, j = lin & 1023;
        if (j > i) {
            float dp = gP[i * 1024 + i] + gP[j * 1024 + j] - 2.f * gP[lin];
            float dt = gT[i * 1024 + i] + gT[j * 1024 + j] - 2.f * gT[lin];
            float c = sqrtf(fmaxf(dp, 0.f)) - sqrtf(fmaxf(dt, 0.f));
            local += c * c;
        }
    }
#pragma unroll
    for (int off = 32; off > 0; off >>= 1) local += __shfl_down(local, off);
    __shared__ float wsum[4];
    if ((tid & 63) == 0) wsum[tid >> 6] = local;
    __syncthreads();
    if (tid == 0) partial[blockIdx.x] = wsum[0] + wsum[1] + wsum[2] + wsum[3];
}

extern "C" void kernel_launch(void* const* d_in, const int* in_sizes, int n_in,
                              void* d_out, int out_size, void* d_ws, size_t ws_size,
                              hipStream_t stream) {
    const float* pred = (const float*)d_in[0];
    const float* tgt  = (const float*)d_in[1];
    // layout: i8 buf [2048*8192 B] 16 MB | part fp16 33.5 MB | norms f32 2048 | partial f32 512
    const size_t q_bytes    = (size_t)2048 * 8192;
    const size_t part_bytes = (size_t)1024 * 16384 * 2;
    const size_t need = q_bytes + part_bytes + (2048 + 512) * sizeof(float);
    if (ws_size >= need) {
        char* qbuf     = (char*)d_ws;
        __half* part   = (__half*)((char*)d_ws + q_bytes);
        float* norms   = (float*)((char*)part + part_bytes);
        float* partial = norms + 2048;
        hipMemsetAsync(norms, 0, 2048 * sizeof(float), stream);
        convert_kernel<<<4096, 256, 0, stream>>>(pred, tgt, qbuf);
        gram_kernel<<<1024, 512, 0, stream>>>(qbuf, part, norms);
        loss_store_kernel<<<512, 256, 0, stream>>>(part, norms, partial);
        finalize_kernel<512><<<1, 256, 0, stream>>>(partial, (float*)d_out);
    } else {
        float* gram    = (float*)d_ws;                  // 8 MB dense
        float* partial = (float*)d_ws + (size_t)2 * 1024 * 1024;
        hipMemsetAsync(gram, 0, (size_t)2 * 1024 * 1024 * sizeof(float), stream);
        gram_fb<<<1024, 512, 0, stream>>>(pred, tgt, gram);
        loss_atomic_kernel<<<1024, 256, 0, stream>>>(gram, partial);
        finalize_kernel<1024><<<1, 256, 0, stream>>>(partial, (float*)d_out);
    }
}